// Round 1
// 2180.924 us; speedup vs baseline: 1.3044x; 1.3044x over previous
//
#include <hip/hip_runtime.h>
#include <cstdint>

// ---------------- common types / helpers ----------------
typedef short s16x8 __attribute__((ext_vector_type(8)));
typedef __bf16 b16x8 __attribute__((ext_vector_type(8)));
typedef float f32x4 __attribute__((ext_vector_type(4)));

#define TSEQ 2048
#define EDIM 1024

__device__ __forceinline__ short f2bf(float x) {  // RTNE float->bf16
  unsigned u = __float_as_uint(x);
  unsigned r = (u + 0x7FFFu + ((u >> 16) & 1u)) >> 16;
  return (short)r;
}

__device__ __forceinline__ f32x4 mfma16(s16x8 a, s16x8 b, f32x4 c) {
  return __builtin_amdgcn_mfma_f32_16x16x32_bf16(
      __builtin_bit_cast(b16x8, a), __builtin_bit_cast(b16x8, b), c, 0, 0, 0);
}

// async global->LDS, 16B/lane; lds base wave-uniform, lane i -> base + i*16
__device__ __forceinline__ void gl_lds16(void* lds, const void* g) {
  __builtin_amdgcn_global_load_lds(
      (const __attribute__((address_space(1))) void*)g,
      (__attribute__((address_space(3))) void*)lds, 16, 0, 0);
}

// ---------------- weight transpose + fp32->bf16 convert ----------------
__global__ __launch_bounds__(256) void cvtT(
    const float* __restrict__ W, short* __restrict__ WT, int K, int N) {
  int t = blockIdx.x;
  const int tn = N >> 5;
  const int bn = (t % tn) << 5, bk = (t / tn) << 5;
  __shared__ float tile[32][33];
  const int tx = threadIdx.x & 31, ty = threadIdx.x >> 5;
#pragma unroll
  for (int i = 0; i < 4; ++i)
    tile[ty + i * 8][tx] = W[(size_t)(bk + ty + i * 8) * N + bn + tx];
  __syncthreads();
#pragma unroll
  for (int i = 0; i < 4; ++i)
    WT[(size_t)(bn + ty + i * 8) * K + bk + tx] = f2bf(tile[tx][ty + i * 8]);
}

// ---------------- layernorm: fp32 in -> bf16 out ----------------
__global__ __launch_bounds__(256) void ln_kernel(
    const float* __restrict__ h, const float* __restrict__ w,
    const float* __restrict__ b, short* __restrict__ y) {
  const int row = blockIdx.x, tid = threadIdx.x;
  const float4 v = ((const float4*)(h + (size_t)row * EDIM))[tid];
  float s = v.x + v.y + v.z + v.w;
  float s2 = v.x * v.x + v.y * v.y + v.z * v.z + v.w * v.w;
#pragma unroll
  for (int off = 1; off < 64; off <<= 1) {
    s += __shfl_xor(s, off, 64);
    s2 += __shfl_xor(s2, off, 64);
  }
  __shared__ float red[8];
  const int wave = tid >> 6, lane = tid & 63;
  if (lane == 0) { red[wave] = s; red[4 + wave] = s2; }
  __syncthreads();
  s = red[0] + red[1] + red[2] + red[3];
  s2 = red[4] + red[5] + red[6] + red[7];
  const float mu = s * (1.f / EDIM);
  const float var = s2 * (1.f / EDIM) - mu * mu;
  const float rstd = rsqrtf(var + 1e-5f);
  const float4 wv = ((const float4*)w)[tid];
  const float4 bv = ((const float4*)b)[tid];
  short4 o = make_short4(f2bf((v.x - mu) * rstd * wv.x + bv.x),
                         f2bf((v.y - mu) * rstd * wv.y + bv.y),
                         f2bf((v.z - mu) * rstd * wv.z + bv.z),
                         f2bf((v.w - mu) * rstd * wv.w + bv.w));
  ((short4*)(y + (size_t)row * EDIM))[tid] = o;
}

// ---------------- GEMM: C[M,N] = A[M,K](bf16) * BT[N,K]^T + bias ----------------
// BMx128 tile, BK=32, 4 waves, global_load_lds 16B staging (m97 structure).
// EPI 0: QKV split  EPI 1: += resid, fp32 out  EPI 2: gelu, bf16 out
template <int EPI, int BM>
__global__ __launch_bounds__(256, 2) void gemm_bt(
    const short* __restrict__ A, const short* __restrict__ BT,
    const float* __restrict__ bias, short* __restrict__ out_bf,
    short* __restrict__ vt, float* __restrict__ out_f,
    const float* __restrict__ resid, int M, int N, int K) {
  constexpr int WM = BM / 2;    // wave tile rows
  constexpr int NMI = WM / 16;  // acc row count
  __shared__ __align__(16) short As[BM * 32];
  __shared__ __align__(16) short Bs[128 * 32];
  const int tid = threadIdx.x;
  const int wave = tid >> 6, lane = tid & 63;
  const int quad = lane >> 4, l16 = lane & 15;
  const int wr = (wave >> 1) * WM, wc = (wave & 1) * 64;
  const int m0 = blockIdx.y * BM, n0 = blockIdx.x * 128;

  const int srow = tid >> 2, scol = (tid & 3) * 8;  // lane -> (row, 16B chunk)
  const short* Ag = A + (size_t)(m0 + srow) * K + scol;
  const short* Bg = BT + (size_t)(n0 + srow) * K + scol;
  short* As0 = &As[wave * 512];
  short* Bs0 = &Bs[wave * 512];
  short* Bs1 = &Bs[2048 + wave * 512];

  f32x4 acc[NMI][4] = {};
  for (int k0 = 0; k0 < K; k0 += 32) {
    gl_lds16(As0, Ag + k0);
    if (BM == 128) gl_lds16(&As[2048 + wave * 512], Ag + (size_t)64 * K + k0);
    gl_lds16(Bs0, Bg + k0);
    gl_lds16(Bs1, Bg + (size_t)64 * K + k0);
    __syncthreads();
    s16x8 af[NMI], bfr[4];
#pragma unroll
    for (int i = 0; i < NMI; ++i)
      af[i] = *(const s16x8*)&As[(wr + i * 16 + l16) * 32 + quad * 8];
#pragma unroll
    for (int i = 0; i < 4; ++i)
      bfr[i] = *(const s16x8*)&Bs[(wc + i * 16 + l16) * 32 + quad * 8];
#pragma unroll
    for (int mi = 0; mi < NMI; ++mi)
#pragma unroll
      for (int ni = 0; ni < 4; ++ni)
        acc[mi][ni] = mfma16(af[mi], bfr[ni], acc[mi][ni]);
    __syncthreads();
  }

#pragma unroll
  for (int mi = 0; mi < NMI; ++mi) {
#pragma unroll
    for (int ni = 0; ni < 4; ++ni) {
      const int col = n0 + wc + ni * 16 + l16;
      const float bv = bias[col];
#pragma unroll
      for (int r = 0; r < 4; ++r) {
        const int row = m0 + wr + mi * 16 + quad * 4 + r;
        float v = acc[mi][ni][r] + bv;
        if (EPI == 1) {
          const size_t idx = (size_t)row * N + col;
          out_f[idx] = v + resid[idx];
        } else if (EPI == 2) {
          const float u = 0.7978845608028654f * (v + 0.044715f * v * v * v);
          out_bf[(size_t)row * N + col] = f2bf(0.5f * v * (1.f + tanhf(u)));
        } else {  // QKV
          if (col < 2048)
            out_bf[(size_t)row * 2048 + col] = f2bf(v);
          else
            vt[(size_t)(col - 2048) * TSEQ + row] = f2bf(v);  // V^T [1024][T]
        }
      }
    }
  }
}

// ---------------- fused causal flash attention ----------------
// 4 waves / block, 64 q-rows (16/wave). K and V^T tiles staged cooperatively
// into LDS with global_load_lds (linear dest) + inverse-XOR-swizzled global
// source; reads apply the same XOR -> conflict-free ds_read_b128.
// P buffer is wave-private -> no barrier between P write and PV read.
// Grid (32,16): head y and y+8 at same x get depths s and 31-s (sum const)
// so each CU's 2 blocks carry uniform combined causal work.
__global__ __launch_bounds__(256) void attn_fused(
    const short* __restrict__ qk,  // [T][2048]: q cols h*64.., k cols 1024+h*64..
    const short* __restrict__ vt,  // [1024][T] = V^T rows (h*64+dh)
    short* __restrict__ aout) {    // [T][1024] bf16
  const int head = blockIdx.y;
  const int sidx = (blockIdx.x + 4 * (head & 7)) & 31;
  const int qg = (head < 8) ? sidx : 31 - sidx;  // q-group 0..31 (64 rows each)
  const int qbase = qg << 6;
  const int qt_end = qg >> 1;  // last 128-wide kv tile (causal); exact for all waves

  const int tid = threadIdx.x;
  const int wave = tid >> 6, lane = tid & 63;
  const int quad = lane >> 4, l16 = lane & 15;
  const int qrow = qbase + wave * 16;

  __shared__ __align__(16) short Ks[128 * 64];     // [krow][dh], XOR-swz, 16 KB
  __shared__ __align__(16) short Vs[64 * 128];     // [dh][kcol], XOR-swz, 16 KB
  __shared__ __align__(16) short ps[4][16 * 136];  // per-wave P tile, padded
  short* psw = ps[wave];

  s16x8 qf[2];
#pragma unroll
  for (int ks = 0; ks < 2; ++ks)
    qf[ks] = *(const s16x8*)&qk[(size_t)(qrow + l16) * 2048 +
                                head * 64 + ks * 32 + quad * 8];

  // staging: thread tid writes LDS byte c*4096 + tid*16 (HW-linear); source
  // chunk is XOR'd so that a swizzled read comes back conflict-free.
  const int krow_off = tid >> 3;                       // 0..31 (row within 32-row call)
  const int kchk = ((tid & 7) ^ (krow_off & 7)) * 8;   // K src chunk (elements)
  const int vrow_off = tid >> 4;                       // 0..15
  const int vchk = ((tid & 15) ^ vrow_off) * 8;        // V src chunk (elements)

  const float scale = 0.125f;  // 1/sqrt(64)
  float mrow[4], lrow[4];
  f32x4 oacc[4] = {};
#pragma unroll
  for (int r = 0; r < 4; ++r) { mrow[r] = -1e30f; lrow[r] = 0.f; }

  for (int kt = 0; kt <= qt_end; ++kt) {
    const int k0 = kt << 7;
    // ---- stage K[128][64] + V^T[64][128] (32 KB, all 4 waves) ----
#pragma unroll
    for (int c = 0; c < 4; ++c) {
      gl_lds16(&Ks[c * 2048 + wave * 512],
               qk + (size_t)(k0 + c * 32 + krow_off) * 2048 + 1024 + head * 64 + kchk);
      gl_lds16(&Vs[c * 2048 + wave * 512],
               vt + (size_t)(head * 64 + c * 16 + vrow_off) * TSEQ + k0 + vchk);
    }
    __syncthreads();  // drains vmcnt: tiles resident

    // ---- QK^T ----
    f32x4 s[8] = {};
    __builtin_amdgcn_s_setprio(1);
#pragma unroll
    for (int ni = 0; ni < 8; ++ni) {
      const int kr = ni * 16 + l16;
      const int sw = kr & 7;
      s16x8 kf0 = *(const s16x8*)((const char*)Ks + kr * 128 + ((quad ^ sw) << 4));
      s16x8 kf1 = *(const s16x8*)((const char*)Ks + kr * 128 + ((quad ^ 4 ^ sw) << 4));
      s[ni] = mfma16(qf[0], kf0, s[ni]);
      s[ni] = mfma16(qf[1], kf1, s[ni]);
    }
    __builtin_amdgcn_s_setprio(0);

    // ---- online softmax (identical math to previous version) ----
    const bool diag = (kt == qt_end);
    float rmax[4] = {-1e30f, -1e30f, -1e30f, -1e30f};
#pragma unroll
    for (int ni = 0; ni < 8; ++ni)
#pragma unroll
      for (int r = 0; r < 4; ++r) {
        float v = s[ni][r] * scale;
        if (diag) {
          const int qa = qrow + quad * 4 + r;
          const int ka = k0 + ni * 16 + l16;
          if (ka > qa) v = -1e30f;
        }
        s[ni][r] = v;
        rmax[r] = fmaxf(rmax[r], v);
      }
#pragma unroll
    for (int off = 1; off < 16; off <<= 1)
#pragma unroll
      for (int r = 0; r < 4; ++r)
        rmax[r] = fmaxf(rmax[r], __shfl_xor(rmax[r], off, 64));
    float al[4];
#pragma unroll
    for (int r = 0; r < 4; ++r) {
      const float mnew = fmaxf(mrow[r], rmax[r]);
      al[r] = __expf(mrow[r] - mnew);
      mrow[r] = mnew;
      lrow[r] *= al[r];
    }
#pragma unroll
    for (int ni = 0; ni < 4; ++ni)
#pragma unroll
      for (int r = 0; r < 4; ++r) oacc[ni][r] *= al[r];
    float psum[4] = {};
#pragma unroll
    for (int ni = 0; ni < 8; ++ni)
#pragma unroll
      for (int r = 0; r < 4; ++r) {
        const float p = __expf(s[ni][r] - mrow[r]);
        psum[r] += p;
        psw[(quad * 4 + r) * 136 + ni * 16 + l16] = f2bf(p);
      }
#pragma unroll
    for (int off = 1; off < 16; off <<= 1)
#pragma unroll
      for (int r = 0; r < 4; ++r) psum[r] += __shfl_xor(psum[r], off, 64);
#pragma unroll
    for (int r = 0; r < 4; ++r) lrow[r] += psum[r];

    // ---- PV (P is wave-private: no barrier needed, compiler orders LDS) ----
    __builtin_amdgcn_s_setprio(1);
#pragma unroll
    for (int ks = 0; ks < 4; ++ks) {
      s16x8 pa = *(const s16x8*)&psw[l16 * 136 + ks * 32 + quad * 8];
#pragma unroll
      for (int ni = 0; ni < 4; ++ni) {
        const int vr = ni * 16 + l16;
        s16x8 vf = *(const s16x8*)((const char*)Vs + vr * 256 +
                                   ((((ks << 2) | quad) ^ (vr & 15)) << 4));
        oacc[ni] = mfma16(pa, vf, oacc[ni]);
      }
    }
    __builtin_amdgcn_s_setprio(0);
    __syncthreads();  // all waves done with Ks/Vs before next stage
  }

#pragma unroll
  for (int ni = 0; ni < 4; ++ni)
#pragma unroll
    for (int r = 0; r < 4; ++r) {
      const int qa = qrow + quad * 4 + r;
      aout[(size_t)qa * EDIM + head * 64 + ni * 16 + l16] =
          f2bf(oacc[ni][r] / lrow[r]);
    }
}

// ---------------- launch ----------------
extern "C" void kernel_launch(void* const* d_in, const int* in_sizes, int n_in,
                              void* d_out, int out_size, void* d_ws, size_t ws_size,
                              hipStream_t stream) {
  const float* x     = (const float*)d_in[0];
  const float* ln1w  = (const float*)d_in[1];
  const float* ln1b  = (const float*)d_in[2];
  const float* attw  = (const float*)d_in[3];
  const float* attb  = (const float*)d_in[4];
  const float* projw = (const float*)d_in[5];
  const float* projb = (const float*)d_in[6];
  const float* ln2w  = (const float*)d_in[7];
  const float* ln2b  = (const float*)d_in[8];
  const float* fcw   = (const float*)d_in[9];
  const float* fcb   = (const float*)d_in[10];
  const float* fc2w  = (const float*)d_in[11];
  const float* fc2b  = (const float*)d_in[12];

  // 36 MB pool, liveness-based reuse
  char* ws = (char*)d_ws;
  float* h   = (float*)(ws);               // [0,8)   residual fp32, persistent
  short* y   = (short*)(ws + (8u << 20));  // [8,12)  LN out bf16 / att (reused)
  short* att = (short*)(ws + (8u << 20));
  short* qkb = (short*)(ws + (12u << 20)); // [12,20) q,k bf16 [T][2048]
  short* vt  = (short*)(ws + (20u << 20)); // [20,24) V^T bf16 [1024][T]
  short* mid = (short*)(ws + (12u << 20)); // [12,28) gelu(fc) bf16 (reuses qkb/vt)
  short* wT  = (short*)(ws + (28u << 20)); // [28,36) JIT-transposed weights

  hipMemcpyAsync(h, x, (size_t)TSEQ * EDIM * 4, hipMemcpyDeviceToDevice, stream);

  for (int l = 0; l < 8; ++l) {
    // ---- attention ----
    ln_kernel<<<TSEQ, 256, 0, stream>>>(h, ln1w + l * 1024, ln1b + l * 1024, y);
    cvtT<<<(3072 / 32) * (1024 / 32), 256, 0, stream>>>(
        attw + (size_t)l * 1024 * 3072, wT, 1024, 3072);
    gemm_bt<0, 128><<<dim3(24, 16), 256, 0, stream>>>(
        y, wT, attb + l * 3072, qkb, vt, nullptr, nullptr, 2048, 3072, 1024);
    attn_fused<<<dim3(32, 16), 256, 0, stream>>>(qkb, vt, att);
    cvtT<<<(1024 / 32) * (1024 / 32), 256, 0, stream>>>(
        projw + (size_t)l * 1024 * 1024, wT, 1024, 1024);
    gemm_bt<1, 64><<<dim3(8, 32), 256, 0, stream>>>(
        att, wT, projb + l * 1024, nullptr, nullptr, h, h, 2048, 1024, 1024);
    // ---- MLP ----
    ln_kernel<<<TSEQ, 256, 0, stream>>>(h, ln2w + l * 1024, ln2b + l * 1024, y);
    cvtT<<<(4096 / 32) * (1024 / 32), 256, 0, stream>>>(
        fcw + (size_t)l * 1024 * 4096, wT, 1024, 4096);
    gemm_bt<2, 128><<<dim3(32, 16), 256, 0, stream>>>(
        y, wT, fcb + l * 4096, mid, nullptr, nullptr, nullptr, 2048, 4096, 1024);
    cvtT<<<(1024 / 32) * (4096 / 32), 256, 0, stream>>>(
        fc2w + (size_t)l * 4096 * 1024, wT, 4096, 1024);
    gemm_bt<1, 64><<<dim3(8, 32), 256, 0, stream>>>(
        mid, wT, fc2b + l * 1024, nullptr, nullptr, h, h, 2048, 1024, 4096);
  }

  hipMemcpyAsync(d_out, h, (size_t)TSEQ * EDIM * 4, hipMemcpyDeviceToDevice, stream);
}

// Round 2
// 1827.468 us; speedup vs baseline: 1.5567x; 1.1934x over previous
//
#include <hip/hip_runtime.h>
#include <cstdint>

// ---------------- common types / helpers ----------------
typedef short s16x8 __attribute__((ext_vector_type(8)));
typedef __bf16 b16x8 __attribute__((ext_vector_type(8)));
typedef float f32x4 __attribute__((ext_vector_type(4)));

#define TSEQ 2048
#define EDIM 1024

__device__ __forceinline__ short f2bf(float x) {  // RTNE float->bf16
  unsigned u = __float_as_uint(x);
  unsigned r = (u + 0x7FFFu + ((u >> 16) & 1u)) >> 16;
  return (short)r;
}

__device__ __forceinline__ f32x4 mfma16(s16x8 a, s16x8 b, f32x4 c) {
  return __builtin_amdgcn_mfma_f32_16x16x32_bf16(
      __builtin_bit_cast(b16x8, a), __builtin_bit_cast(b16x8, b), c, 0, 0, 0);
}

// async global->LDS, 16B/lane; lds base wave-uniform, lane i -> base + i*16
__device__ __forceinline__ void gl_lds16(void* lds, const void* g) {
  __builtin_amdgcn_global_load_lds(
      (const __attribute__((address_space(1))) void*)g,
      (__attribute__((address_space(3))) void*)lds, 16, 0, 0);
}

// ---------------- weight transpose + fp32->bf16 convert ----------------
__global__ __launch_bounds__(256) void cvtT(
    const float* __restrict__ W, short* __restrict__ WT, int K, int N) {
  int t = blockIdx.x;
  const int tn = N >> 5;
  const int bn = (t % tn) << 5, bk = (t / tn) << 5;
  __shared__ float tile[32][33];
  const int tx = threadIdx.x & 31, ty = threadIdx.x >> 5;
#pragma unroll
  for (int i = 0; i < 4; ++i)
    tile[ty + i * 8][tx] = W[(size_t)(bk + ty + i * 8) * N + bn + tx];
  __syncthreads();
#pragma unroll
  for (int i = 0; i < 4; ++i)
    WT[(size_t)(bn + ty + i * 8) * K + bk + tx] = f2bf(tile[tx][ty + i * 8]);
}

// ---------------- layernorm: fp32 in -> bf16 out ----------------
__global__ __launch_bounds__(256) void ln_kernel(
    const float* __restrict__ h, const float* __restrict__ w,
    const float* __restrict__ b, short* __restrict__ y) {
  const int row = blockIdx.x, tid = threadIdx.x;
  const float4 v = ((const float4*)(h + (size_t)row * EDIM))[tid];
  float s = v.x + v.y + v.z + v.w;
  float s2 = v.x * v.x + v.y * v.y + v.z * v.z + v.w * v.w;
#pragma unroll
  for (int off = 1; off < 64; off <<= 1) {
    s += __shfl_xor(s, off, 64);
    s2 += __shfl_xor(s2, off, 64);
  }
  __shared__ float red[8];
  const int wave = tid >> 6, lane = tid & 63;
  if (lane == 0) { red[wave] = s; red[4 + wave] = s2; }
  __syncthreads();
  s = red[0] + red[1] + red[2] + red[3];
  s2 = red[4] + red[5] + red[6] + red[7];
  const float mu = s * (1.f / EDIM);
  const float var = s2 * (1.f / EDIM) - mu * mu;
  const float rstd = rsqrtf(var + 1e-5f);
  const float4 wv = ((const float4*)w)[tid];
  const float4 bv = ((const float4*)b)[tid];
  short4 o = make_short4(f2bf((v.x - mu) * rstd * wv.x + bv.x),
                         f2bf((v.y - mu) * rstd * wv.y + bv.y),
                         f2bf((v.z - mu) * rstd * wv.z + bv.z),
                         f2bf((v.w - mu) * rstd * wv.w + bv.w));
  ((short4*)(y + (size_t)row * EDIM))[tid] = o;
}

// ---------------- GEMM: C[M,N] = A[M,K](bf16) * BT[N,K]^T + bias ----------------
// BMx128 tile, BK=64, 4 waves, double-buffered LDS, 2-phase pipeline:
// STAGE(t+1) issued before compute(t), ONE barrier per K-step (T3 minimum
// 2-phase recipe). LDS reads XOR-swizzled (inverse swizzle applied to the
// global_load_lds SOURCE, linear dest -- rule #21) -> even 8-deep bank load.
// EPI 0: QKV split  EPI 1: atomicAdd into out_f (split-K; z==0 adds bias)
// EPI 2: gelu, bf16 out
template <int EPI, int BM>
__global__ __launch_bounds__(256, 2) void gemm_bt(
    const short* __restrict__ A, const short* __restrict__ BT,
    const float* __restrict__ bias, short* __restrict__ out_bf,
    short* __restrict__ vt, float* __restrict__ out_f,
    int M, int N, int K) {
  constexpr int WM = BM / 2;    // wave tile rows
  constexpr int NMI = WM / 16;  // acc row count
  constexpr int ASZ = BM * 64;  // shorts per A buffer
  constexpr int BSZ = 128 * 64;
  __shared__ __align__(16) short As[2 * ASZ];
  __shared__ __align__(16) short Bs[2 * BSZ];
  const int tid = threadIdx.x;
  const int wave = tid >> 6, lane = tid & 63;
  const int quad = lane >> 4, l16 = lane & 15;
  const int wr = (wave >> 1) * WM, wc = (wave & 1) * 64;
  const int m0 = blockIdx.y * BM, n0 = blockIdx.x * 128;
  const int ksplit = K / gridDim.z;  // K-range per z-slice
  const int kbase = blockIdx.z * ksplit;

  // staging source (per-lane), chunk XOR-swizzled so linear-dest LDS reads
  // back conflict-free with the same XOR on the read side.
  const int r8 = lane >> 3, c8 = lane & 7;
  const int csw = (c8 ^ r8) << 3;  // element offset within 64-elem row
  const short* Ag = A + (size_t)(m0 + wave * (BM / 4) + r8) * K + kbase + csw;
  const short* Bg = BT + (size_t)(n0 + wave * 32 + r8) * K + kbase + csw;

  f32x4 acc[NMI][4] = {};
  const int NT = ksplit >> 6;

  // prologue: stage tile 0 into buffer 0
#pragma unroll
  for (int c = 0; c < BM / 32; ++c)
    gl_lds16(&As[(wave * (BM / 32) + c) * 512], Ag + (size_t)(8 * c) * K);
#pragma unroll
  for (int c = 0; c < 4; ++c)
    gl_lds16(&Bs[(wave * 4 + c) * 512], Bg + (size_t)(8 * c) * K);
  __syncthreads();

  int cur = 0;
  for (int t = 0; t < NT; ++t) {
    if (t + 1 < NT) {  // issue next-tile stage into buf cur^1 (overlaps MFMA)
      const size_t ko = (size_t)(t + 1) << 6;
#pragma unroll
      for (int c = 0; c < BM / 32; ++c)
        gl_lds16(&As[(cur ^ 1) * ASZ + (wave * (BM / 32) + c) * 512],
                 Ag + (size_t)(8 * c) * K + ko);
#pragma unroll
      for (int c = 0; c < 4; ++c)
        gl_lds16(&Bs[(cur ^ 1) * BSZ + (wave * 4 + c) * 512],
                 Bg + (size_t)(8 * c) * K + ko);
    }
    const short* Ab = &As[cur * ASZ];
    const short* Bb = &Bs[cur * BSZ];
    const int rsw = l16 & 7;
    s16x8 af[NMI][2], bfr[4][2];
#pragma unroll
    for (int i = 0; i < NMI; ++i)
#pragma unroll
      for (int ks = 0; ks < 2; ++ks)
        af[i][ks] = *(const s16x8*)&Ab[(wr + i * 16 + l16) * 64 +
                                       ((((ks << 2) | quad) ^ rsw) << 3)];
#pragma unroll
    for (int i = 0; i < 4; ++i)
#pragma unroll
      for (int ks = 0; ks < 2; ++ks)
        bfr[i][ks] = *(const s16x8*)&Bb[(wc + i * 16 + l16) * 64 +
                                        ((((ks << 2) | quad) ^ rsw) << 3)];
#pragma unroll
    for (int mi = 0; mi < NMI; ++mi)
#pragma unroll
      for (int ni = 0; ni < 4; ++ni)
#pragma unroll
        for (int ks = 0; ks < 2; ++ks)
          acc[mi][ni] = mfma16(af[mi][ks], bfr[ni][ks], acc[mi][ni]);
    __syncthreads();  // drains vmcnt: next buffer resident; LDS reads done
    cur ^= 1;
  }

#pragma unroll
  for (int mi = 0; mi < NMI; ++mi) {
#pragma unroll
    for (int ni = 0; ni < 4; ++ni) {
      const int col = n0 + wc + ni * 16 + l16;
      const float bv = (EPI == 1 && blockIdx.z != 0) ? 0.f : bias[col];
#pragma unroll
      for (int r = 0; r < 4; ++r) {
        const int row = m0 + wr + mi * 16 + quad * 4 + r;
        float v = acc[mi][ni][r] + bv;
        if (EPI == 1) {  // split-K accumulate; out_f already holds residual
          atomicAdd(&out_f[(size_t)row * N + col], v);
        } else if (EPI == 2) {
          const float u = 0.7978845608028654f * (v + 0.044715f * v * v * v);
          const float e = __expf(2.f * u);  // tanh(u) = 1 - 2/(e^{2u}+1)
          const float th = 1.f - 2.f / (e + 1.f);
          out_bf[(size_t)row * N + col] = f2bf(0.5f * v * (1.f + th));
        } else {  // QKV
          if (col < 2048)
            out_bf[(size_t)row * 2048 + col] = f2bf(v);
          else
            vt[(size_t)(col - 2048) * TSEQ + row] = f2bf(v);  // V^T [1024][T]
        }
      }
    }
  }
}

// ---------------- fused causal flash attention ----------------
// 4 waves / block, 64 q-rows (16/wave). K and V^T tiles staged cooperatively
// into LDS with global_load_lds (linear dest) + inverse-XOR-swizzled global
// source; reads apply the same XOR -> conflict-free ds_read_b128.
// P buffer is wave-private -> no barrier between P write and PV read.
// Grid (32,16): head y and y+8 at same x get depths s and 31-s (sum const)
// so each CU's 2 blocks carry uniform combined causal work.
__global__ __launch_bounds__(256) void attn_fused(
    const short* __restrict__ qk,  // [T][2048]: q cols h*64.., k cols 1024+h*64..
    const short* __restrict__ vt,  // [1024][T] = V^T rows (h*64+dh)
    short* __restrict__ aout) {    // [T][1024] bf16
  const int head = blockIdx.y;
  const int sidx = (blockIdx.x + 4 * (head & 7)) & 31;
  const int qg = (head < 8) ? sidx : 31 - sidx;  // q-group 0..31 (64 rows each)
  const int qbase = qg << 6;
  const int qt_end = qg >> 1;  // last 128-wide kv tile (causal)

  const int tid = threadIdx.x;
  const int wave = tid >> 6, lane = tid & 63;
  const int quad = lane >> 4, l16 = lane & 15;
  const int qrow = qbase + wave * 16;

  __shared__ __align__(16) short Ks[128 * 64];     // [krow][dh], XOR-swz, 16 KB
  __shared__ __align__(16) short Vs[64 * 128];     // [dh][kcol], XOR-swz, 16 KB
  __shared__ __align__(16) short ps[4][16 * 136];  // per-wave P tile, padded
  short* psw = ps[wave];

  s16x8 qf[2];
#pragma unroll
  for (int ks = 0; ks < 2; ++ks)
    qf[ks] = *(const s16x8*)&qk[(size_t)(qrow + l16) * 2048 +
                                head * 64 + ks * 32 + quad * 8];

  const int krow_off = tid >> 3;                       // 0..31
  const int kchk = ((tid & 7) ^ (krow_off & 7)) * 8;   // K src chunk (elements)
  const int vrow_off = tid >> 4;                       // 0..15
  const int vchk = ((tid & 15) ^ vrow_off) * 8;        // V src chunk (elements)

  const float scale = 0.125f;  // 1/sqrt(64)
  float mrow[4], lrow[4];
  f32x4 oacc[4] = {};
#pragma unroll
  for (int r = 0; r < 4; ++r) { mrow[r] = -1e30f; lrow[r] = 0.f; }

  for (int kt = 0; kt <= qt_end; ++kt) {
    const int k0 = kt << 7;
    // ---- stage K[128][64] + V^T[64][128] (32 KB, all 4 waves) ----
#pragma unroll
    for (int c = 0; c < 4; ++c) {
      gl_lds16(&Ks[c * 2048 + wave * 512],
               qk + (size_t)(k0 + c * 32 + krow_off) * 2048 + 1024 + head * 64 + kchk);
      gl_lds16(&Vs[c * 2048 + wave * 512],
               vt + (size_t)(head * 64 + c * 16 + vrow_off) * TSEQ + k0 + vchk);
    }
    __syncthreads();  // drains vmcnt: tiles resident

    // ---- QK^T ----
    f32x4 s[8] = {};
    __builtin_amdgcn_s_setprio(1);
#pragma unroll
    for (int ni = 0; ni < 8; ++ni) {
      const int kr = ni * 16 + l16;
      const int sw = kr & 7;
      s16x8 kf0 = *(const s16x8*)((const char*)Ks + kr * 128 + ((quad ^ sw) << 4));
      s16x8 kf1 = *(const s16x8*)((const char*)Ks + kr * 128 + ((quad ^ 4 ^ sw) << 4));
      s[ni] = mfma16(qf[0], kf0, s[ni]);
      s[ni] = mfma16(qf[1], kf1, s[ni]);
    }
    __builtin_amdgcn_s_setprio(0);

    // ---- online softmax ----
    const bool diag = (kt == qt_end);
    float rmax[4] = {-1e30f, -1e30f, -1e30f, -1e30f};
#pragma unroll
    for (int ni = 0; ni < 8; ++ni)
#pragma unroll
      for (int r = 0; r < 4; ++r) {
        float v = s[ni][r] * scale;
        if (diag) {
          const int qa = qrow + quad * 4 + r;
          const int ka = k0 + ni * 16 + l16;
          if (ka > qa) v = -1e30f;
        }
        s[ni][r] = v;
        rmax[r] = fmaxf(rmax[r], v);
      }
#pragma unroll
    for (int off = 1; off < 16; off <<= 1)
#pragma unroll
      for (int r = 0; r < 4; ++r)
        rmax[r] = fmaxf(rmax[r], __shfl_xor(rmax[r], off, 64));
    float al[4];
#pragma unroll
    for (int r = 0; r < 4; ++r) {
      const float mnew = fmaxf(mrow[r], rmax[r]);
      al[r] = __expf(mrow[r] - mnew);
      mrow[r] = mnew;
      lrow[r] *= al[r];
    }
#pragma unroll
    for (int ni = 0; ni < 4; ++ni)
#pragma unroll
      for (int r = 0; r < 4; ++r) oacc[ni][r] *= al[r];
    float psum[4] = {};
#pragma unroll
    for (int ni = 0; ni < 8; ++ni)
#pragma unroll
      for (int r = 0; r < 4; ++r) {
        const float p = __expf(s[ni][r] - mrow[r]);
        psum[r] += p;
        psw[(quad * 4 + r) * 136 + ni * 16 + l16] = f2bf(p);
      }
#pragma unroll
    for (int off = 1; off < 16; off <<= 1)
#pragma unroll
      for (int r = 0; r < 4; ++r) psum[r] += __shfl_xor(psum[r], off, 64);
#pragma unroll
    for (int r = 0; r < 4; ++r) lrow[r] += psum[r];

    // ---- PV (P wave-private: no barrier needed) ----
    __builtin_amdgcn_s_setprio(1);
#pragma unroll
    for (int ks = 0; ks < 4; ++ks) {
      s16x8 pa = *(const s16x8*)&psw[l16 * 136 + ks * 32 + quad * 8];
#pragma unroll
      for (int ni = 0; ni < 4; ++ni) {
        const int vr = ni * 16 + l16;
        s16x8 vf = *(const s16x8*)((const char*)Vs + vr * 256 +
                                   ((((ks << 2) | quad) ^ (vr & 15)) << 4));
        oacc[ni] = mfma16(pa, vf, oacc[ni]);
      }
    }
    __builtin_amdgcn_s_setprio(0);
    __syncthreads();  // all waves done with Ks/Vs before next stage
  }

#pragma unroll
  for (int ni = 0; ni < 4; ++ni)
#pragma unroll
    for (int r = 0; r < 4; ++r) {
      const int qa = qrow + quad * 4 + r;
      aout[(size_t)qa * EDIM + head * 64 + ni * 16 + l16] =
          f2bf(oacc[ni][r] / lrow[r]);
    }
}

// ---------------- launch ----------------
extern "C" void kernel_launch(void* const* d_in, const int* in_sizes, int n_in,
                              void* d_out, int out_size, void* d_ws, size_t ws_size,
                              hipStream_t stream) {
  const float* x     = (const float*)d_in[0];
  const float* ln1w  = (const float*)d_in[1];
  const float* ln1b  = (const float*)d_in[2];
  const float* attw  = (const float*)d_in[3];
  const float* attb  = (const float*)d_in[4];
  const float* projw = (const float*)d_in[5];
  const float* projb = (const float*)d_in[6];
  const float* ln2w  = (const float*)d_in[7];
  const float* ln2b  = (const float*)d_in[8];
  const float* fcw   = (const float*)d_in[9];
  const float* fcb   = (const float*)d_in[10];
  const float* fc2w  = (const float*)d_in[11];
  const float* fc2b  = (const float*)d_in[12];

  // 36 MB pool, liveness-based reuse
  char* ws = (char*)d_ws;
  float* h   = (float*)(ws);               // [0,8)   residual fp32, persistent
  short* y   = (short*)(ws + (8u << 20));  // [8,12)  LN out bf16 / att (reused)
  short* att = (short*)(ws + (8u << 20));
  short* qkb = (short*)(ws + (12u << 20)); // [12,20) q,k bf16 [T][2048]
  short* vt  = (short*)(ws + (20u << 20)); // [20,24) V^T bf16 [1024][T]
  short* mid = (short*)(ws + (12u << 20)); // [12,28) gelu(fc) bf16 (reuses qkb/vt)
  short* wT  = (short*)(ws + (28u << 20)); // [28,36) JIT-transposed weights

  hipMemcpyAsync(h, x, (size_t)TSEQ * EDIM * 4, hipMemcpyDeviceToDevice, stream);

  for (int l = 0; l < 8; ++l) {
    // ---- attention ----
    ln_kernel<<<TSEQ, 256, 0, stream>>>(h, ln1w + l * 1024, ln1b + l * 1024, y);
    cvtT<<<(3072 / 32) * (1024 / 32), 256, 0, stream>>>(
        attw + (size_t)l * 1024 * 3072, wT, 1024, 3072);
    gemm_bt<0, 128><<<dim3(24, 16, 1), 256, 0, stream>>>(
        y, wT, attb + l * 3072, qkb, vt, nullptr, 2048, 3072, 1024);
    attn_fused<<<dim3(32, 16), 256, 0, stream>>>(qkb, vt, att);
    cvtT<<<(1024 / 32) * (1024 / 32), 256, 0, stream>>>(
        projw + (size_t)l * 1024 * 1024, wT, 1024, 1024);
    gemm_bt<1, 64><<<dim3(8, 32, 2), 256, 0, stream>>>(
        att, wT, projb + l * 1024, nullptr, nullptr, h, 2048, 1024, 1024);
    // ---- MLP ----
    ln_kernel<<<TSEQ, 256, 0, stream>>>(h, ln2w + l * 1024, ln2b + l * 1024, y);
    cvtT<<<(4096 / 32) * (1024 / 32), 256, 0, stream>>>(
        fcw + (size_t)l * 1024 * 4096, wT, 1024, 4096);
    gemm_bt<2, 128><<<dim3(32, 16, 1), 256, 0, stream>>>(
        y, wT, fcb + l * 4096, mid, nullptr, nullptr, 2048, 4096, 1024);
    cvtT<<<(1024 / 32) * (4096 / 32), 256, 0, stream>>>(
        fc2w + (size_t)l * 4096 * 1024, wT, 4096, 1024);
    gemm_bt<1, 64><<<dim3(8, 32, 2), 256, 0, stream>>>(
        mid, wT, fc2b + l * 1024, nullptr, nullptr, h, 2048, 1024, 4096);
  }

  hipMemcpyAsync(d_out, h, (size_t)TSEQ * EDIM * 4, hipMemcpyDeviceToDevice, stream);
}